// Round 1
// baseline (615.316 us; speedup 1.0000x reference)
//
#include <hip/hip_runtime.h>
#include <math.h>

// Problem dims (fixed by reference)
#define BB   64
#define NN   8192
#define FF   128
#define HH   512
#define GG   2048
#define EE   256
#define VV   10000
#define EPSF 1e-6f

// Workspace layout (floats)
static constexpr size_t OFF_GPART = 0;                       // 4*2048*64 = 524288
static constexpr size_t OFF_H2    = OFF_GPART + 524288;      // 32768
static constexpr size_t OFF_OCAT  = OFF_H2    + 32768;       // 524*64 = 33536
static constexpr size_t OFF_PAR   = OFF_OCAT  + 33536;       // 64*544 = 34816
static constexpr size_t OFF_ZW    = OFF_PAR   + 34816;       // 524288
static constexpr size_t OFF_SR    = OFF_ZW    + 524288;      // 524288*8 = 4194304
static constexpr size_t OFF_WW    = OFF_SR    + 4194304;     // 524288
static constexpr size_t OFF_WR    = OFF_WW    + 524288;      // 524288
static constexpr size_t OFF_WRWW  = OFF_WR    + 524288;      // 524288
static constexpr size_t OFF_PT    = OFF_WRWW  + 524288;      // 2048*256 = 524288
static constexpr size_t OFF_T3    = OFF_PT    + 524288;      // 64
static constexpr size_t OFF_RVEC  = OFF_T3    + 64;          // 8192
// total = 7449408 floats ~ 29.8 MB

__device__ __forceinline__ float sigmoidf_(float x){ return 1.f/(1.f + __expf(-x)); }
__device__ __forceinline__ float softplusf_(float x){ return (x > 20.f) ? x : log1pf(__expf(x)); }

// ---------------- K1: g = X @ [W_ih|W_hh]^T partials (K-split by 4) --------
__global__ __launch_bounds__(256) void lstm_gemm_kernel(
    const int* __restrict__ x, const float* __restrict__ h,
    const float* __restrict__ emb, const float* __restrict__ Wih,
    const float* __restrict__ Whh, float* __restrict__ gpart)
{
  __shared__ float X[64*193];
  const int tid = threadIdx.x;
  const int jt = blockIdx.x;      // 64 tiles of 32 j
  const int kc = blockIdx.y;      // 4 chunks of 192 k
  const int k0 = kc*192;
  for (int idx = tid; idx < 64*192; idx += 256){
    int bb = idx / 192, k = idx - bb*192;
    int kg = k0 + k;
    float v = (kg < EE) ? emb[(size_t)x[bb]*EE + kg] : h[bb*HH + (kg - EE)];
    X[bb*193 + k] = v;
  }
  __syncthreads();
  const int wv = tid >> 6, lane = tid & 63;
  const int j0 = jt*32 + wv*8;
  float acc[8] = {0.f,0.f,0.f,0.f,0.f,0.f,0.f,0.f};
  for (int k = 0; k < 192; ++k){
    const float xv = X[lane*193 + k];
    const int kg = k0 + k;
    #pragma unroll
    for (int jj = 0; jj < 8; ++jj){
      const int j = j0 + jj;
      const float w = (kg < EE) ? Wih[j*EE + kg] : Whh[j*HH + (kg - EE)];
      acc[jj] = fmaf(w, xv, acc[jj]);
    }
  }
  #pragma unroll
  for (int jj = 0; jj < 8; ++jj)
    gpart[(size_t)kc*131072 + (size_t)(j0+jj)*64 + lane] = acc[jj];
}

// ---------------- K2: reduce partials + LSTM activations -> h2 -------------
__global__ __launch_bounds__(256) void lstm_act_kernel(
    const float* __restrict__ gpart, const float* __restrict__ bih,
    const float* __restrict__ bhh, const float* __restrict__ c,
    float* __restrict__ h2)
{
  const int idx = blockIdx.x*256 + threadIdx.x;   // 32768
  const int bb = idx & 63, hh = idx >> 6;
  float gi = bih[hh]        + bhh[hh];
  float gf = bih[512+hh]    + bhh[512+hh];
  float gg = bih[1024+hh]   + bhh[1024+hh];
  float go = bih[1536+hh]   + bhh[1536+hh];
  #pragma unroll
  for (int kc = 0; kc < 4; ++kc){
    const float* gp = gpart + (size_t)kc*131072;
    gi += gp[(size_t)(hh)*64 + bb];
    gf += gp[(size_t)(512+hh)*64 + bb];
    gg += gp[(size_t)(1024+hh)*64 + bb];
    go += gp[(size_t)(1536+hh)*64 + bb];
  }
  float c0 = c[bb*HH + hh];
  float c2 = sigmoidf_(gf)*c0 + sigmoidf_(gi)*tanhf(gg);
  h2[bb*HH + hh] = sigmoidf_(go)*tanhf(c2);
}

// ---------------- K3: o_cat[524][64] = h2 @ [W_write;W_read]^T + bias ------
__global__ __launch_bounds__(256) void head_gemm_kernel(
    const float* __restrict__ h2, const float* __restrict__ Ww,
    const float* __restrict__ bw, const float* __restrict__ Wr,
    const float* __restrict__ br, float* __restrict__ ocat)
{
  __shared__ float Xs[64*129];
  const int tid = threadIdx.x;
  const int wv = tid >> 6, lane = tid & 63;
  const int j0 = blockIdx.x*32 + wv*8;
  float acc[8];
  #pragma unroll
  for (int jj = 0; jj < 8; ++jj){
    int j = j0 + jj;
    acc[jj] = (j < 390) ? bw[j] : (j < 524 ? br[j-390] : 0.f);
  }
  for (int c4 = 0; c4 < 4; ++c4){
    __syncthreads();
    for (int idx = tid; idx < 64*128; idx += 256){
      int bb = idx >> 7, k = idx & 127;
      Xs[bb*129 + k] = h2[bb*HH + c4*128 + k];
    }
    __syncthreads();
    for (int k = 0; k < 128; ++k){
      const float xv = Xs[lane*129 + k];
      const int kg = c4*128 + k;
      #pragma unroll
      for (int jj = 0; jj < 8; ++jj){
        const int j = j0 + jj;
        if (j < 524){
          const float w = (j < 390) ? Ww[j*HH + kg] : Wr[(j-390)*HH + kg];
          acc[jj] = fmaf(w, xv, acc[jj]);
        }
      }
    }
  }
  #pragma unroll
  for (int jj = 0; jj < 8; ++jj){
    int j = j0 + jj;
    if (j < 524) ocat[(size_t)j*64 + lane] = acc[jj];
  }
}

// ---------------- K4: interpret heads -> params[b] -------------------------
// params stride 544: [0:128] kwE, [128:256] krE, [256:384] a, [384:512] e,
// 512+: {beta_w,g_w,sw0,sw1,sw2,r_w, beta_r,g_r,sr0,sr1,sr2,r_r, nkw,nkr,C_akr,Ca2}
__global__ void interpret_kernel(const float* __restrict__ ocat,
                                 float* __restrict__ params)
{
  const int b = blockIdx.x, l = threadIdx.x;   // 64 threads
  float* P = params + (size_t)b*544;
  float skw = 0.f, skr = 0.f, sakr = 0.f, sa2 = 0.f;
  #pragma unroll
  for (int f = l; f < 128; f += 64){
    float kwE = ocat[(size_t)f*64 + b] + EPSF;
    float ee  = sigmoidf_(ocat[(size_t)(134+f)*64 + b]);
    float aa  = ocat[(size_t)(262+f)*64 + b];
    float krE = ocat[(size_t)(390+f)*64 + b] + EPSF;
    P[f] = kwE; P[128+f] = krE; P[256+f] = aa; P[384+f] = ee;
    skw = fmaf(kwE,kwE,skw); skr = fmaf(krE,krE,skr);
    sakr = fmaf(aa,krE,sakr); sa2 = fmaf(aa,aa,sa2);
  }
  #pragma unroll
  for (int m = 32; m >= 1; m >>= 1){
    skw += __shfl_xor(skw,m); skr += __shfl_xor(skr,m);
    sakr += __shfl_xor(sakr,m); sa2 += __shfl_xor(sa2,m);
  }
  if (l == 0){
    P[512+0] = softplusf_(ocat[(size_t)128*64 + b]);
    P[512+1] = sigmoidf_(ocat[(size_t)129*64 + b]);
    {
      float x0 = ocat[(size_t)130*64+b], x1 = ocat[(size_t)131*64+b], x2 = ocat[(size_t)132*64+b];
      float mm = fmaxf(x0, fmaxf(x1, x2));
      float e0 = __expf(x0-mm), e1 = __expf(x1-mm), e2 = __expf(x2-mm);
      float s = e0+e1+e2;
      P[512+2] = e0/s; P[512+3] = e1/s; P[512+4] = e2/s;
    }
    P[512+5] = 1.f + softplusf_(ocat[(size_t)133*64 + b]);
    P[512+6] = softplusf_(ocat[(size_t)518*64 + b]);
    P[512+7] = sigmoidf_(ocat[(size_t)519*64 + b]);
    {
      float x0 = ocat[(size_t)520*64+b], x1 = ocat[(size_t)521*64+b], x2 = ocat[(size_t)522*64+b];
      float mm = fmaxf(x0, fmaxf(x1, x2));
      float e0 = __expf(x0-mm), e1 = __expf(x1-mm), e2 = __expf(x2-mm);
      float s = e0+e1+e2;
      P[512+8] = e0/s; P[512+9] = e1/s; P[512+10] = e2/s;
    }
    P[512+11] = 1.f + softplusf_(ocat[(size_t)523*64 + b]);
    P[512+12] = sqrtf(skw); P[512+13] = sqrtf(skr);
    P[512+14] = sakr;       P[512+15] = sa2;
  }
}

// ---------------- K5: big pass A — per-row scalars over bank ---------------
// per row: zw = beta_w * cos-sim(bank,kw) ; Sr[8] = {S2,S3,S4,S5,S6,S7,S8,0}
__global__ __launch_bounds__(256) void pass_a_kernel(
    const float* __restrict__ bank, const float* __restrict__ params,
    float* __restrict__ zw, float* __restrict__ Sr)
{
  const int blk = blockIdx.x;            // 2048 = 64 b * 32 chunks
  const int b = blk >> 5, chunk = blk & 31;
  const int tid = threadIdx.x;
  const int wv = tid >> 6, lane = tid & 63;
  const int fslot = lane & 7, rsub = lane >> 3;   // 8 lanes per row, 16 f each
  const float* P = params + (size_t)b*544;
  const int fb = fslot << 4;
  float kw[16], kr[16], av[16], ev[16];
  #pragma unroll
  for (int i = 0; i < 16; ++i){
    kw[i] = P[fb+i]; kr[i] = P[128+fb+i]; av[i] = P[256+fb+i]; ev[i] = P[384+fb+i];
  }
  const float beta_w = P[512+0], nkw = P[512+12];
  for (int it = 0; it < 8; ++it){
    const int n = (chunk << 8) + (it << 5) + (wv << 3) + rsub;
    const size_t row = (size_t)b*NN + n;
    const float4* m4 = reinterpret_cast<const float4*>(bank + row*FF + fb);
    float mv[16];
    *reinterpret_cast<float4*>(&mv[0])  = m4[0];
    *reinterpret_cast<float4*>(&mv[4])  = m4[1];
    *reinterpret_cast<float4*>(&mv[8])  = m4[2];
    *reinterpret_cast<float4*>(&mv[12]) = m4[3];
    float s1=0.f,s2=0.f,s3=0.f,s4=0.f,s5=0.f,s6=0.f,s7=0.f,s8=0.f;
    #pragma unroll
    for (int i = 0; i < 16; ++i){
      const float m = mv[i], u = m + EPSF, em = ev[i]*m;
      s1 = fmaf(u,kw[i],s1);  s2 = fmaf(u,u,s2);
      s3 = fmaf(u,kr[i],s3);  s4 = fmaf(em,kr[i],s4);
      s5 = fmaf(u,av[i],s5);  s6 = fmaf(u,em,s6);
      s7 = fmaf(av[i],em,s7); s8 = fmaf(em,em,s8);
    }
    #pragma unroll
    for (int mm = 1; mm < 8; mm <<= 1){
      s1 += __shfl_xor(s1,mm); s2 += __shfl_xor(s2,mm);
      s3 += __shfl_xor(s3,mm); s4 += __shfl_xor(s4,mm);
      s5 += __shfl_xor(s5,mm); s6 += __shfl_xor(s6,mm);
      s7 += __shfl_xor(s7,mm); s8 += __shfl_xor(s8,mm);
    }
    if (fslot == 0){
      float sim = s1 / fmaxf(sqrtf(s2)*nkw, 1e-8f);
      zw[row] = beta_w * sim;
      float4* o = reinterpret_cast<float4*>(Sr + row*8);
      o[0] = make_float4(s2,s3,s4,s5);
      o[1] = make_float4(s6,s7,s8,0.f);
    }
  }
}

// ---------------- block reductions for K6 ----------------------------------
__device__ __forceinline__ float blockMax1024(float v, float* red, int tid){
  #pragma unroll
  for (int m = 32; m >= 1; m >>= 1) v = fmaxf(v, __shfl_xor(v,m));
  __syncthreads();
  if ((tid & 63) == 0) red[tid >> 6] = v;
  __syncthreads();
  if (tid == 0){
    float r = red[0];
    #pragma unroll
    for (int i = 1; i < 16; ++i) r = fmaxf(r, red[i]);
    red[16] = r;
  }
  __syncthreads();
  return red[16];
}
__device__ __forceinline__ float blockSum1024(float v, float* red, int tid){
  #pragma unroll
  for (int m = 32; m >= 1; m >>= 1) v += __shfl_xor(v,m);
  __syncthreads();
  if ((tid & 63) == 0) red[tid >> 6] = v;
  __syncthreads();
  if (tid == 0){
    float r = 0.f;
    #pragma unroll
    for (int i = 0; i < 16; ++i) r += red[i];
    red[16] = r;
  }
  __syncthreads();
  return red[16];
}

// ---------------- K6: per-batch softmax/conv/sharpen pipeline x2 -----------
__global__ __launch_bounds__(1024) void head_pipeline_kernel(
    const float* __restrict__ zw, const float* __restrict__ Sr,
    const float* __restrict__ w_write, const float* __restrict__ w_read,
    const float* __restrict__ params,
    float* __restrict__ wwg, float* __restrict__ wrg,
    float* __restrict__ wrwwg, float* __restrict__ T3g)
{
  __shared__ float wa[NN];
  __shared__ float red[32];
  const int b = blockIdx.x;
  const int tid = threadIdx.x;
  const float* P = params + (size_t)b*544 + 512;
  const float g_w = P[1], sw0 = P[2], sw1 = P[3], sw2 = P[4], r_w = P[5];
  const float beta_r = P[6], g_r = P[7], sr0 = P[8], sr1 = P[9], sr2 = P[10], r_r = P[11];
  const float nkr = P[13], C_akr = P[14], Ca2 = P[15];
  const size_t base = (size_t)b*NN;
  float cv[8], wwreg[8];

  // ======== write head ========
  float lm = -1e30f;
  #pragma unroll
  for (int i = 0; i < 8; ++i){ int n = tid + (i<<10); float z = zw[base+n]; wa[n] = z; lm = fmaxf(lm,z); }
  float M = blockMax1024(lm, red, tid);
  float ls = 0.f;
  #pragma unroll
  for (int i = 0; i < 8; ++i){ int n = tid + (i<<10); float e = __expf(wa[n]-M); wa[n] = e; ls += e; }
  float S = blockSum1024(ls, red, tid);
  const float invS = 1.f/S;
  #pragma unroll
  for (int i = 0; i < 8; ++i){ int n = tid + (i<<10); wa[n] = wa[n]*invS + (1.f-g_w)*w_write[base+n]; }
  __syncthreads();
  #pragma unroll
  for (int i = 0; i < 8; ++i){ int n = tid + (i<<10);
    cv[i] = sw0*wa[(n+NN-1)&(NN-1)] + sw1*wa[n] + sw2*wa[(n+1)&(NN-1)]; }
  __syncthreads();
  float lp = 0.f;
  #pragma unroll
  for (int i = 0; i < 8; ++i){ int n = tid + (i<<10); float p = __expf(r_w*__logf(cv[i])); wa[n] = p; lp += p; }
  float Sp = blockSum1024(lp, red, tid);
  float inv = 1.f/(Sp + EPSF);
  #pragma unroll
  for (int i = 0; i < 8; ++i){ int n = tid + (i<<10); float ww = wa[n]*inv; wwreg[i] = ww; wwg[base+n] = ww; }
  __syncthreads();

  // ======== read head (bank2 stats reconstructed from Sr + ww) ========
  lm = -1e30f;
  #pragma unroll
  for (int i = 0; i < 8; ++i){
    int n = tid + (i<<10);
    const size_t row = base + n;
    const float4* s4 = reinterpret_cast<const float4*>(Sr) + row*2;
    float4 A = s4[0], Bv = s4[1];   // {S2,S3,S4,S5}, {S6,S7,S8,-}
    float ww = wwreg[i];
    float num = A.y + ww*(C_akr - A.z);
    float d2  = A.x + 2.f*ww*(A.w - Bv.x) + ww*ww*(Ca2 - 2.f*Bv.y + Bv.z);
    float den = sqrtf(d2)*nkr;
    float z = beta_r * (num / fmaxf(den, 1e-8f));
    wa[n] = z; lm = fmaxf(lm,z);
  }
  M = blockMax1024(lm, red, tid);
  ls = 0.f;
  #pragma unroll
  for (int i = 0; i < 8; ++i){ int n = tid + (i<<10); float e = __expf(wa[n]-M); wa[n] = e; ls += e; }
  S = blockSum1024(ls, red, tid);
  const float invS2 = 1.f/S;
  #pragma unroll
  for (int i = 0; i < 8; ++i){ int n = tid + (i<<10); wa[n] = wa[n]*invS2 + (1.f-g_r)*w_read[base+n]; }
  __syncthreads();
  #pragma unroll
  for (int i = 0; i < 8; ++i){ int n = tid + (i<<10);
    cv[i] = sr0*wa[(n+NN-1)&(NN-1)] + sr1*wa[n] + sr2*wa[(n+1)&(NN-1)]; }
  __syncthreads();
  lp = 0.f;
  #pragma unroll
  for (int i = 0; i < 8; ++i){ int n = tid + (i<<10); float p = __expf(r_r*__logf(cv[i])); wa[n] = p; lp += p; }
  Sp = blockSum1024(lp, red, tid);
  inv = 1.f/(Sp + EPSF);
  float t3 = 0.f;
  #pragma unroll
  for (int i = 0; i < 8; ++i){
    int n = tid + (i<<10);
    float wr_ = wa[n]*inv;
    wrg[base+n] = wr_;
    float xx = wr_*wwreg[i];
    wrwwg[base+n] = xx;
    t3 += xx;
  }
  float T3 = blockSum1024(t3, red, tid);
  if (tid == 0) T3g[b] = T3;
}

// ---------------- K7: big pass D — weighted reductions over bank -----------
__global__ __launch_bounds__(256) void pass_d_kernel(
    const float* __restrict__ bank, const float* __restrict__ wrg,
    const float* __restrict__ wrwwg, float* __restrict__ pT)
{
  const int blk = blockIdx.x;           // 2048 = 64 b * 32 chunks
  const int b = blk >> 5, chunk = blk & 31;
  const int tid = threadIdx.x;
  const int st = tid >> 5, li = tid & 31;   // 8 row-streams, 32 f4 each
  float4 a1 = make_float4(0.f,0.f,0.f,0.f);
  float4 a2 = make_float4(0.f,0.f,0.f,0.f);
  for (int it = 0; it < 32; ++it){
    const int n = (chunk << 8) + (it << 3) + st;
    const size_t row = (size_t)b*NN + n;
    const float w1 = wrg[row], w2 = wrwwg[row];
    const float4 m = reinterpret_cast<const float4*>(bank + row*FF)[li];
    a1.x = fmaf(w1,m.x,a1.x); a1.y = fmaf(w1,m.y,a1.y);
    a1.z = fmaf(w1,m.z,a1.z); a1.w = fmaf(w1,m.w,a1.w);
    a2.x = fmaf(w2,m.x,a2.x); a2.y = fmaf(w2,m.y,a2.y);
    a2.z = fmaf(w2,m.z,a2.z); a2.w = fmaf(w2,m.w,a2.w);
  }
  __shared__ float lds[8*256];
  *reinterpret_cast<float4*>(&lds[st*256 + li*4]) = a1;
  *reinterpret_cast<float4*>(&lds[st*256 + 128 + li*4]) = a2;
  __syncthreads();
  float s = 0.f;
  #pragma unroll
  for (int k = 0; k < 8; ++k) s += lds[k*256 + tid];
  pT[(size_t)blk*256 + tid] = s;
}

// ---------------- K7b: reduce partials -> rvec ------------------------------
__global__ __launch_bounds__(256) void rvec_kernel(
    const float* __restrict__ pT, const float* __restrict__ params,
    const float* __restrict__ T3g, float* __restrict__ rvec)
{
  const int gid = blockIdx.x*256 + threadIdx.x;   // 8192
  const int b = gid >> 7, f = gid & 127;
  float t1 = 0.f, t2 = 0.f;
  for (int cc = 0; cc < 32; ++cc){
    const float* p = pT + (size_t)((b<<5) + cc)*256;
    t1 += p[f]; t2 += p[128+f];
  }
  const float* P = params + (size_t)b*544;
  rvec[gid] = t1 - P[384+f]*t2 + P[256+f]*T3g[b];
}

// ---------------- K8: out = rvec @ W_out^T + b_out --------------------------
__global__ __launch_bounds__(256) void out_gemm_kernel(
    const float* __restrict__ rvec, const float* __restrict__ Wout,
    const float* __restrict__ bout, float* __restrict__ out)
{
  const int tid = threadIdx.x;
  const int wv = tid >> 6, lane = tid & 63;     // lane = batch
  const int j0 = blockIdx.x*32 + wv*8;
  float acc[8];
  #pragma unroll
  for (int jj = 0; jj < 8; ++jj){ int j = j0 + jj; acc[jj] = (j < VV) ? bout[j] : 0.f; }
  for (int fc = 0; fc < 128; fc += 32){
    float rv[32];
    #pragma unroll
    for (int i = 0; i < 32; ++i) rv[i] = rvec[lane*128 + fc + i];
    #pragma unroll
    for (int jj = 0; jj < 8; ++jj){
      const int j = j0 + jj;
      if (j < VV){
        const float* w = Wout + (size_t)j*128 + fc;
        #pragma unroll
        for (int i = 0; i < 32; ++i) acc[jj] = fmaf(w[i], rv[i], acc[jj]);
      }
    }
  }
  #pragma unroll
  for (int jj = 0; jj < 8; ++jj){
    int j = j0 + jj;
    if (j < VV) out[(size_t)lane*VV + j] = acc[jj];
  }
}

// ---------------------------------------------------------------------------
extern "C" void kernel_launch(void* const* d_in, const int* in_sizes, int n_in,
                              void* d_out, int out_size, void* d_ws, size_t ws_size,
                              hipStream_t stream)
{
  const int*   x       = (const int*)  d_in[0];
  const float* h       = (const float*)d_in[1];
  const float* c       = (const float*)d_in[2];
  const float* w_read  = (const float*)d_in[3];
  const float* w_write = (const float*)d_in[4];
  const float* bank    = (const float*)d_in[5];
  const float* emb     = (const float*)d_in[6];
  const float* Wih     = (const float*)d_in[7];
  const float* bih     = (const float*)d_in[8];
  const float* Whh     = (const float*)d_in[9];
  const float* bhh     = (const float*)d_in[10];
  const float* Wr      = (const float*)d_in[11];
  const float* br      = (const float*)d_in[12];
  const float* Ww      = (const float*)d_in[13];
  const float* bw      = (const float*)d_in[14];
  const float* Wout    = (const float*)d_in[15];
  const float* bout    = (const float*)d_in[16];
  float* out = (float*)d_out;
  float* ws  = (float*)d_ws;

  float* gpart = ws + OFF_GPART;
  float* h2    = ws + OFF_H2;
  float* ocat  = ws + OFF_OCAT;
  float* par   = ws + OFF_PAR;
  float* zwp   = ws + OFF_ZW;
  float* Srp   = ws + OFF_SR;
  float* wwp   = ws + OFF_WW;
  float* wrp   = ws + OFF_WR;
  float* wrwwp = ws + OFF_WRWW;
  float* pTp   = ws + OFF_PT;
  float* T3p   = ws + OFF_T3;
  float* rvp   = ws + OFF_RVEC;

  hipLaunchKernelGGL(lstm_gemm_kernel,   dim3(64,4), dim3(256), 0, stream, x, h, emb, Wih, Whh, gpart);
  hipLaunchKernelGGL(lstm_act_kernel,    dim3(128),  dim3(256), 0, stream, gpart, bih, bhh, c, h2);
  hipLaunchKernelGGL(head_gemm_kernel,   dim3(17),   dim3(256), 0, stream, h2, Ww, bw, Wr, br, ocat);
  hipLaunchKernelGGL(interpret_kernel,   dim3(64),   dim3(64),  0, stream, ocat, par);
  hipLaunchKernelGGL(pass_a_kernel,      dim3(2048), dim3(256), 0, stream, bank, par, zwp, Srp);
  hipLaunchKernelGGL(head_pipeline_kernel, dim3(64), dim3(1024),0, stream, zwp, Srp, w_write, w_read, par, wwp, wrp, wrwwp, T3p);
  hipLaunchKernelGGL(pass_d_kernel,      dim3(2048), dim3(256), 0, stream, bank, wrp, wrwwp, pTp);
  hipLaunchKernelGGL(rvec_kernel,        dim3(32),   dim3(256), 0, stream, pTp, par, T3p, rvp);
  hipLaunchKernelGGL(out_gemm_kernel,    dim3(313),  dim3(256), 0, stream, rvp, Wout, bout, out);
}

// Round 2
// 227.298 us; speedup vs baseline: 2.7071x; 2.7071x over previous
//
#include <hip/hip_runtime.h>
#include <math.h>

// Problem dims (fixed by reference)
#define BB   64
#define NN   8192
#define FF   128
#define HH   512
#define GG   2048
#define EE   256
#define VV   10000
#define EPSF 1e-6f

// Workspace layout (floats)
static constexpr size_t OFF_XT    = 0;                       // 768*64   = 49152
static constexpr size_t OFF_G     = OFF_XT   + 49152;        // 2048*64  = 131072
static constexpr size_t OFF_H2T   = OFF_G    + 131072;       // 512*64   = 32768
static constexpr size_t OFF_OCAT  = OFF_H2T  + 32768;        // 524*64   = 33536
static constexpr size_t OFF_PAR   = OFF_OCAT + 33536;        // 64*544   = 34816
static constexpr size_t OFF_ZW    = OFF_PAR  + 34816;        // 524288
static constexpr size_t OFF_SR    = OFF_ZW   + 524288;       // 4194304
static constexpr size_t OFF_WW    = OFF_SR   + 4194304;      // 524288
static constexpr size_t OFF_WR    = OFF_WW   + 524288;       // 524288
static constexpr size_t OFF_WRWW  = OFF_WR   + 524288;       // 524288
static constexpr size_t OFF_PT    = OFF_WRWW + 524288;       // 2048*256 = 524288
static constexpr size_t OFF_T3    = OFF_PT   + 524288;       // 64
static constexpr size_t OFF_RVEC  = OFF_T3   + 64;           // 8192

__device__ __forceinline__ float sigmoidf_(float x){ return 1.f/(1.f + __expf(-x)); }
__device__ __forceinline__ float softplusf_(float x){ return (x > 20.f) ? x : log1pf(__expf(x)); }

// ---------------- K0: gather Xt[k][b] = concat(emb[x[b]], h[b]) transposed --
__global__ __launch_bounds__(256) void gather_xt_kernel(
    const int* __restrict__ x, const float* __restrict__ h,
    const float* __restrict__ emb, float* __restrict__ Xt)
{
  const int idx = blockIdx.x*256 + threadIdx.x;    // 49152 = 768*64
  const int k = idx >> 6, b = idx & 63;
  float v = (k < EE) ? emb[(size_t)x[b]*EE + k] : h[(size_t)b*HH + (k - EE)];
  Xt[(size_t)k*64 + b] = v;
}

// ---------------- K1: gates g[j][b] = W_row_j . X_b + biases (wave per j) --
__global__ __launch_bounds__(256) void lstm_gates_kernel(
    const float* __restrict__ Xt, const float* __restrict__ Wih,
    const float* __restrict__ bih, const float* __restrict__ Whh,
    const float* __restrict__ bhh, float* __restrict__ g)
{
  const int tid = threadIdx.x;
  const int wv = __builtin_amdgcn_readfirstlane(tid >> 6);
  const int lane = tid & 63;
  const int j = blockIdx.x*4 + wv;                 // 2048 rows
  const float* wi = Wih + (size_t)j*EE;
  const float* wh = Whh + (size_t)j*HH;
  float acc = bih[j] + bhh[j];
  #pragma unroll 8
  for (int k = 0; k < EE; ++k)
    acc = fmaf(wi[k], Xt[(size_t)k*64 + lane], acc);
  #pragma unroll 8
  for (int k = 0; k < HH; ++k)
    acc = fmaf(wh[k], Xt[(size_t)(EE+k)*64 + lane], acc);
  g[(size_t)j*64 + lane] = acc;
}

// ---------------- K2: LSTM activations -> h2t[hh][bb] ----------------------
__global__ __launch_bounds__(256) void lstm_act_kernel(
    const float* __restrict__ g, const float* __restrict__ c,
    float* __restrict__ h2t)
{
  const int idx = blockIdx.x*256 + threadIdx.x;   // 32768
  const int bb = idx & 63, hh = idx >> 6;
  const float gi = g[(size_t)(hh)*64 + bb];
  const float gf = g[(size_t)(512+hh)*64 + bb];
  const float gg = g[(size_t)(1024+hh)*64 + bb];
  const float go = g[(size_t)(1536+hh)*64 + bb];
  const float c0 = c[(size_t)bb*HH + hh];
  const float c2 = sigmoidf_(gf)*c0 + sigmoidf_(gi)*tanhf(gg);
  h2t[(size_t)hh*64 + bb] = sigmoidf_(go)*tanhf(c2);
}

// ---------------- K3: ocat[j][b] = [W_write;W_read]_j . h2_b + bias --------
__global__ __launch_bounds__(256) void head_gemm_kernel(
    const float* __restrict__ h2t, const float* __restrict__ Ww,
    const float* __restrict__ bw, const float* __restrict__ Wr,
    const float* __restrict__ br, float* __restrict__ ocat)
{
  const int tid = threadIdx.x;
  const int wv = __builtin_amdgcn_readfirstlane(tid >> 6);
  const int lane = tid & 63;
  const int j = blockIdx.x*4 + wv;                 // 524 rows (131*4 = 524)
  const float* wrow = (j < 390) ? (Ww + (size_t)j*HH) : (Wr + (size_t)(j-390)*HH);
  float acc = (j < 390) ? bw[j] : br[j-390];
  #pragma unroll 8
  for (int k = 0; k < HH; ++k)
    acc = fmaf(wrow[k], h2t[(size_t)k*64 + lane], acc);
  ocat[(size_t)j*64 + lane] = acc;
}

// ---------------- K4: interpret heads -> params[b] -------------------------
// params stride 544: [0:128] kwE, [128:256] krE, [256:384] a, [384:512] e,
// 512+: {beta_w,g_w,sw0,sw1,sw2,r_w, beta_r,g_r,sr0,sr1,sr2,r_r, nkw,nkr,C_akr,Ca2}
__global__ void interpret_kernel(const float* __restrict__ ocat,
                                 float* __restrict__ params)
{
  const int b = blockIdx.x, l = threadIdx.x;   // 64 threads
  float* P = params + (size_t)b*544;
  float skw = 0.f, skr = 0.f, sakr = 0.f, sa2 = 0.f;
  #pragma unroll
  for (int f = l; f < 128; f += 64){
    float kwE = ocat[(size_t)f*64 + b] + EPSF;
    float ee  = sigmoidf_(ocat[(size_t)(134+f)*64 + b]);
    float aa  = ocat[(size_t)(262+f)*64 + b];
    float krE = ocat[(size_t)(390+f)*64 + b] + EPSF;
    P[f] = kwE; P[128+f] = krE; P[256+f] = aa; P[384+f] = ee;
    skw = fmaf(kwE,kwE,skw); skr = fmaf(krE,krE,skr);
    sakr = fmaf(aa,krE,sakr); sa2 = fmaf(aa,aa,sa2);
  }
  #pragma unroll
  for (int m = 32; m >= 1; m >>= 1){
    skw += __shfl_xor(skw,m); skr += __shfl_xor(skr,m);
    sakr += __shfl_xor(sakr,m); sa2 += __shfl_xor(sa2,m);
  }
  if (l == 0){
    P[512+0] = softplusf_(ocat[(size_t)128*64 + b]);
    P[512+1] = sigmoidf_(ocat[(size_t)129*64 + b]);
    {
      float x0 = ocat[(size_t)130*64+b], x1 = ocat[(size_t)131*64+b], x2 = ocat[(size_t)132*64+b];
      float mm = fmaxf(x0, fmaxf(x1, x2));
      float e0 = __expf(x0-mm), e1 = __expf(x1-mm), e2 = __expf(x2-mm);
      float s = e0+e1+e2;
      P[512+2] = e0/s; P[512+3] = e1/s; P[512+4] = e2/s;
    }
    P[512+5] = 1.f + softplusf_(ocat[(size_t)133*64 + b]);
    P[512+6] = softplusf_(ocat[(size_t)518*64 + b]);
    P[512+7] = sigmoidf_(ocat[(size_t)519*64 + b]);
    {
      float x0 = ocat[(size_t)520*64+b], x1 = ocat[(size_t)521*64+b], x2 = ocat[(size_t)522*64+b];
      float mm = fmaxf(x0, fmaxf(x1, x2));
      float e0 = __expf(x0-mm), e1 = __expf(x1-mm), e2 = __expf(x2-mm);
      float s = e0+e1+e2;
      P[512+8] = e0/s; P[512+9] = e1/s; P[512+10] = e2/s;
    }
    P[512+11] = 1.f + softplusf_(ocat[(size_t)523*64 + b]);
    P[512+12] = sqrtf(skw); P[512+13] = sqrtf(skr);
    P[512+14] = sakr;       P[512+15] = sa2;
  }
}

// ---------------- K5: big pass A — per-row scalars over bank ---------------
// per row: zw = beta_w * cos-sim(bank,kw) ; Sr[8] = {S2,S3,S4,S5,S6,S7,S8,0}
__global__ __launch_bounds__(256) void pass_a_kernel(
    const float* __restrict__ bank, const float* __restrict__ params,
    float* __restrict__ zw, float* __restrict__ Sr)
{
  const int blk = blockIdx.x;            // 2048 = 64 b * 32 chunks
  const int b = blk >> 5, chunk = blk & 31;
  const int tid = threadIdx.x;
  const int wv = tid >> 6, lane = tid & 63;
  const int fslot = lane & 7, rsub = lane >> 3;   // 8 lanes per row, 16 f each
  const float* P = params + (size_t)b*544;
  const int fb = fslot << 4;
  float kw[16], kr[16], av[16], ev[16];
  #pragma unroll
  for (int i = 0; i < 16; ++i){
    kw[i] = P[fb+i]; kr[i] = P[128+fb+i]; av[i] = P[256+fb+i]; ev[i] = P[384+fb+i];
  }
  const float beta_w = P[512+0], nkw = P[512+12];
  for (int it = 0; it < 8; ++it){
    const int n = (chunk << 8) + (it << 5) + (wv << 3) + rsub;
    const size_t row = (size_t)b*NN + n;
    const float4* m4 = reinterpret_cast<const float4*>(bank + row*FF + fb);
    float mv[16];
    *reinterpret_cast<float4*>(&mv[0])  = m4[0];
    *reinterpret_cast<float4*>(&mv[4])  = m4[1];
    *reinterpret_cast<float4*>(&mv[8])  = m4[2];
    *reinterpret_cast<float4*>(&mv[12]) = m4[3];
    float s1=0.f,s2=0.f,s3=0.f,s4=0.f,s5=0.f,s6=0.f,s7=0.f,s8=0.f;
    #pragma unroll
    for (int i = 0; i < 16; ++i){
      const float m = mv[i], u = m + EPSF, em = ev[i]*m;
      s1 = fmaf(u,kw[i],s1);  s2 = fmaf(u,u,s2);
      s3 = fmaf(u,kr[i],s3);  s4 = fmaf(em,kr[i],s4);
      s5 = fmaf(u,av[i],s5);  s6 = fmaf(u,em,s6);
      s7 = fmaf(av[i],em,s7); s8 = fmaf(em,em,s8);
    }
    #pragma unroll
    for (int mm = 1; mm < 8; mm <<= 1){
      s1 += __shfl_xor(s1,mm); s2 += __shfl_xor(s2,mm);
      s3 += __shfl_xor(s3,mm); s4 += __shfl_xor(s4,mm);
      s5 += __shfl_xor(s5,mm); s6 += __shfl_xor(s6,mm);
      s7 += __shfl_xor(s7,mm); s8 += __shfl_xor(s8,mm);
    }
    if (fslot == 0){
      float sim = s1 / fmaxf(sqrtf(s2)*nkw, 1e-8f);
      zw[row] = beta_w * sim;
      float4* o = reinterpret_cast<float4*>(Sr + row*8);
      o[0] = make_float4(s2,s3,s4,s5);
      o[1] = make_float4(s6,s7,s8,0.f);
    }
  }
}

// ---------------- block reductions for K6 ----------------------------------
__device__ __forceinline__ float blockMax1024(float v, float* red, int tid){
  #pragma unroll
  for (int m = 32; m >= 1; m >>= 1) v = fmaxf(v, __shfl_xor(v,m));
  __syncthreads();
  if ((tid & 63) == 0) red[tid >> 6] = v;
  __syncthreads();
  if (tid == 0){
    float r = red[0];
    #pragma unroll
    for (int i = 1; i < 16; ++i) r = fmaxf(r, red[i]);
    red[16] = r;
  }
  __syncthreads();
  return red[16];
}
__device__ __forceinline__ float blockSum1024(float v, float* red, int tid){
  #pragma unroll
  for (int m = 32; m >= 1; m >>= 1) v += __shfl_xor(v,m);
  __syncthreads();
  if ((tid & 63) == 0) red[tid >> 6] = v;
  __syncthreads();
  if (tid == 0){
    float r = 0.f;
    #pragma unroll
    for (int i = 0; i < 16; ++i) r += red[i];
    red[16] = r;
  }
  __syncthreads();
  return red[16];
}

// ---------------- K6: per-batch softmax/conv/sharpen pipeline x2 -----------
__global__ __launch_bounds__(1024) void head_pipeline_kernel(
    const float* __restrict__ zw, const float* __restrict__ Sr,
    const float* __restrict__ w_write, const float* __restrict__ w_read,
    const float* __restrict__ params,
    float* __restrict__ wwg, float* __restrict__ wrg,
    float* __restrict__ wrwwg, float* __restrict__ T3g)
{
  __shared__ float wa[NN];
  __shared__ float red[32];
  const int b = blockIdx.x;
  const int tid = threadIdx.x;
  const float* P = params + (size_t)b*544 + 512;
  const float g_w = P[1], sw0 = P[2], sw1 = P[3], sw2 = P[4], r_w = P[5];
  const float beta_r = P[6], g_r = P[7], sr0 = P[8], sr1 = P[9], sr2 = P[10], r_r = P[11];
  const float nkr = P[13], C_akr = P[14], Ca2 = P[15];
  const size_t base = (size_t)b*NN;
  float cv[8], wwreg[8];

  // ======== write head ========
  float lm = -1e30f;
  #pragma unroll
  for (int i = 0; i < 8; ++i){ int n = tid + (i<<10); float z = zw[base+n]; wa[n] = z; lm = fmaxf(lm,z); }
  float M = blockMax1024(lm, red, tid);
  float ls = 0.f;
  #pragma unroll
  for (int i = 0; i < 8; ++i){ int n = tid + (i<<10); float e = __expf(wa[n]-M); wa[n] = e; ls += e; }
  float S = blockSum1024(ls, red, tid);
  const float invS = 1.f/S;
  #pragma unroll
  for (int i = 0; i < 8; ++i){ int n = tid + (i<<10); wa[n] = wa[n]*invS + (1.f-g_w)*w_write[base+n]; }
  __syncthreads();
  #pragma unroll
  for (int i = 0; i < 8; ++i){ int n = tid + (i<<10);
    cv[i] = sw0*wa[(n+NN-1)&(NN-1)] + sw1*wa[n] + sw2*wa[(n+1)&(NN-1)]; }
  __syncthreads();
  float lp = 0.f;
  #pragma unroll
  for (int i = 0; i < 8; ++i){ int n = tid + (i<<10); float p = __expf(r_w*__logf(cv[i])); wa[n] = p; lp += p; }
  float Sp = blockSum1024(lp, red, tid);
  float inv = 1.f/(Sp + EPSF);
  #pragma unroll
  for (int i = 0; i < 8; ++i){ int n = tid + (i<<10); float ww = wa[n]*inv; wwreg[i] = ww; wwg[base+n] = ww; }
  __syncthreads();

  // ======== read head (bank2 stats reconstructed from Sr + ww) ========
  lm = -1e30f;
  #pragma unroll
  for (int i = 0; i < 8; ++i){
    int n = tid + (i<<10);
    const size_t row = base + n;
    const float4* s4 = reinterpret_cast<const float4*>(Sr) + row*2;
    float4 A = s4[0], Bv = s4[1];   // {S2,S3,S4,S5}, {S6,S7,S8,-}
    float ww = wwreg[i];
    float num = A.y + ww*(C_akr - A.z);
    float d2  = A.x + 2.f*ww*(A.w - Bv.x) + ww*ww*(Ca2 - 2.f*Bv.y + Bv.z);
    float den = sqrtf(d2)*nkr;
    float z = beta_r * (num / fmaxf(den, 1e-8f));
    wa[n] = z; lm = fmaxf(lm,z);
  }
  M = blockMax1024(lm, red, tid);
  ls = 0.f;
  #pragma unroll
  for (int i = 0; i < 8; ++i){ int n = tid + (i<<10); float e = __expf(wa[n]-M); wa[n] = e; ls += e; }
  S = blockSum1024(ls, red, tid);
  const float invS2 = 1.f/S;
  #pragma unroll
  for (int i = 0; i < 8; ++i){ int n = tid + (i<<10); wa[n] = wa[n]*invS2 + (1.f-g_r)*w_read[base+n]; }
  __syncthreads();
  #pragma unroll
  for (int i = 0; i < 8; ++i){ int n = tid + (i<<10);
    cv[i] = sr0*wa[(n+NN-1)&(NN-1)] + sr1*wa[n] + sr2*wa[(n+1)&(NN-1)]; }
  __syncthreads();
  lp = 0.f;
  #pragma unroll
  for (int i = 0; i < 8; ++i){ int n = tid + (i<<10); float p = __expf(r_r*__logf(cv[i])); wa[n] = p; lp += p; }
  Sp = blockSum1024(lp, red, tid);
  inv = 1.f/(Sp + EPSF);
  float t3 = 0.f;
  #pragma unroll
  for (int i = 0; i < 8; ++i){
    int n = tid + (i<<10);
    float wr_ = wa[n]*inv;
    wrg[base+n] = wr_;
    float xx = wr_*wwreg[i];
    wrwwg[base+n] = xx;
    t3 += xx;
  }
  float T3 = blockSum1024(t3, red, tid);
  if (tid == 0) T3g[b] = T3;
}

// ---------------- K7: big pass D — weighted reductions over bank -----------
__global__ __launch_bounds__(256) void pass_d_kernel(
    const float* __restrict__ bank, const float* __restrict__ wrg,
    const float* __restrict__ wrwwg, float* __restrict__ pT)
{
  const int blk = blockIdx.x;           // 2048 = 64 b * 32 chunks
  const int b = blk >> 5, chunk = blk & 31;
  const int tid = threadIdx.x;
  const int st = tid >> 5, li = tid & 31;   // 8 row-streams, 32 f4 each
  float4 a1 = make_float4(0.f,0.f,0.f,0.f);
  float4 a2 = make_float4(0.f,0.f,0.f,0.f);
  for (int it = 0; it < 32; ++it){
    const int n = (chunk << 8) + (it << 3) + st;
    const size_t row = (size_t)b*NN + n;
    const float w1 = wrg[row], w2 = wrwwg[row];
    const float4 m = reinterpret_cast<const float4*>(bank + row*FF)[li];
    a1.x = fmaf(w1,m.x,a1.x); a1.y = fmaf(w1,m.y,a1.y);
    a1.z = fmaf(w1,m.z,a1.z); a1.w = fmaf(w1,m.w,a1.w);
    a2.x = fmaf(w2,m.x,a2.x); a2.y = fmaf(w2,m.y,a2.y);
    a2.z = fmaf(w2,m.z,a2.z); a2.w = fmaf(w2,m.w,a2.w);
  }
  __shared__ float lds[8*256];
  *reinterpret_cast<float4*>(&lds[st*256 + li*4]) = a1;
  *reinterpret_cast<float4*>(&lds[st*256 + 128 + li*4]) = a2;
  __syncthreads();
  float s = 0.f;
  #pragma unroll
  for (int k = 0; k < 8; ++k) s += lds[k*256 + tid];
  pT[(size_t)blk*256 + tid] = s;
}

// ---------------- K7b: reduce partials -> rvec ------------------------------
__global__ __launch_bounds__(256) void rvec_kernel(
    const float* __restrict__ pT, const float* __restrict__ params,
    const float* __restrict__ T3g, float* __restrict__ rvec)
{
  const int gid = blockIdx.x*256 + threadIdx.x;   // 8192
  const int b = gid >> 7, f = gid & 127;
  float t1 = 0.f, t2 = 0.f;
  for (int cc = 0; cc < 32; ++cc){
    const float* p = pT + (size_t)((b<<5) + cc)*256;
    t1 += p[f]; t2 += p[128+f];
  }
  const float* P = params + (size_t)b*544;
  rvec[gid] = t1 - P[384+f]*t2 + P[256+f]*T3g[b];
}

// ---------------- K8: out = rvec @ W_out^T + b_out --------------------------
__global__ __launch_bounds__(256) void out_gemm_kernel(
    const float* __restrict__ rvec, const float* __restrict__ Wout,
    const float* __restrict__ bout, float* __restrict__ out)
{
  const int tid = threadIdx.x;
  const int wv = __builtin_amdgcn_readfirstlane(tid >> 6);
  const int lane = tid & 63;     // lane = batch
  const int j0 = blockIdx.x*32 + wv*8;
  float acc[8];
  #pragma unroll
  for (int jj = 0; jj < 8; ++jj){ int j = j0 + jj; acc[jj] = (j < VV) ? bout[j] : 0.f; }
  for (int fc = 0; fc < 128; fc += 32){
    float rv[32];
    #pragma unroll
    for (int i = 0; i < 32; ++i) rv[i] = rvec[lane*128 + fc + i];
    #pragma unroll
    for (int jj = 0; jj < 8; ++jj){
      const int j = j0 + jj;
      if (j < VV){
        const float* w = Wout + (size_t)j*128 + fc;
        #pragma unroll
        for (int i = 0; i < 32; ++i) acc[jj] = fmaf(w[i], rv[i], acc[jj]);
      }
    }
  }
  #pragma unroll
  for (int jj = 0; jj < 8; ++jj){
    int j = j0 + jj;
    if (j < VV) out[(size_t)lane*VV + j] = acc[jj];
  }
}

// ---------------------------------------------------------------------------
extern "C" void kernel_launch(void* const* d_in, const int* in_sizes, int n_in,
                              void* d_out, int out_size, void* d_ws, size_t ws_size,
                              hipStream_t stream)
{
  const int*   x       = (const int*)  d_in[0];
  const float* h       = (const float*)d_in[1];
  const float* c       = (const float*)d_in[2];
  const float* w_read  = (const float*)d_in[3];
  const float* w_write = (const float*)d_in[4];
  const float* bank    = (const float*)d_in[5];
  const float* emb     = (const float*)d_in[6];
  const float* Wih     = (const float*)d_in[7];
  const float* bih     = (const float*)d_in[8];
  const float* Whh     = (const float*)d_in[9];
  const float* bhh     = (const float*)d_in[10];
  const float* Wr      = (const float*)d_in[11];
  const float* br      = (const float*)d_in[12];
  const float* Ww      = (const float*)d_in[13];
  const float* bw      = (const float*)d_in[14];
  const float* Wout    = (const float*)d_in[15];
  const float* bout    = (const float*)d_in[16];
  float* out = (float*)d_out;
  float* ws  = (float*)d_ws;

  float* Xt    = ws + OFF_XT;
  float* gg    = ws + OFF_G;
  float* h2t   = ws + OFF_H2T;
  float* ocat  = ws + OFF_OCAT;
  float* par   = ws + OFF_PAR;
  float* zwp   = ws + OFF_ZW;
  float* Srp   = ws + OFF_SR;
  float* wwp   = ws + OFF_WW;
  float* wrp   = ws + OFF_WR;
  float* wrwwp = ws + OFF_WRWW;
  float* pTp   = ws + OFF_PT;
  float* T3p   = ws + OFF_T3;
  float* rvp   = ws + OFF_RVEC;

  hipLaunchKernelGGL(gather_xt_kernel,     dim3(192),  dim3(256), 0, stream, x, h, emb, Xt);
  hipLaunchKernelGGL(lstm_gates_kernel,    dim3(512),  dim3(256), 0, stream, Xt, Wih, bih, Whh, bhh, gg);
  hipLaunchKernelGGL(lstm_act_kernel,      dim3(128),  dim3(256), 0, stream, gg, c, h2t);
  hipLaunchKernelGGL(head_gemm_kernel,     dim3(131),  dim3(256), 0, stream, h2t, Ww, bw, Wr, br, ocat);
  hipLaunchKernelGGL(interpret_kernel,     dim3(64),   dim3(64),  0, stream, ocat, par);
  hipLaunchKernelGGL(pass_a_kernel,        dim3(2048), dim3(256), 0, stream, bank, par, zwp, Srp);
  hipLaunchKernelGGL(head_pipeline_kernel, dim3(64),   dim3(1024),0, stream, zwp, Srp, w_write, w_read, par, wwp, wrp, wrwwp, T3p);
  hipLaunchKernelGGL(pass_d_kernel,        dim3(2048), dim3(256), 0, stream, bank, wrp, wrwwp, pTp);
  hipLaunchKernelGGL(rvec_kernel,          dim3(32),   dim3(256), 0, stream, pTp, par, T3p, rvp);
  hipLaunchKernelGGL(out_gemm_kernel,      dim3(313),  dim3(256), 0, stream, rvp, Wout, bout, out);
}

// Round 3
// 209.123 us; speedup vs baseline: 2.9424x; 1.0869x over previous
//
#include <hip/hip_runtime.h>
#include <math.h>

// Problem dims (fixed by reference)
#define BB   64
#define NN   8192
#define FF   128
#define HH   512
#define GG   2048
#define EE   256
#define VV   10000
#define EPSF 1e-6f

// Workspace layout (floats)
static constexpr size_t OFF_XT    = 0;                        // 768*64    = 49152
static constexpr size_t OFF_GPART = 49152;                    // 2*2048*64 = 262144
static constexpr size_t OFF_H2T   = 311296;                   // 512*64    = 32768
static constexpr size_t OFF_HPART = 344064;                   // 2*524*64  = 67072
static constexpr size_t OFF_PAR   = 411136;                   // 64*544    = 34816
static constexpr size_t OFF_ZW    = 445952;                   // 524288
static constexpr size_t OFF_Q4    = 970240;                   // 4*524288 = 2097152 (16B aligned)
static constexpr size_t OFF_Q1    = 3067392;                  // 524288
static constexpr size_t OFF_WR    = 3591680;                  // 524288
static constexpr size_t OFF_WRWW  = 4115968;                  // 524288
static constexpr size_t OFF_PT    = 4640256;                  // 2048*256 = 524288
static constexpr size_t OFF_T3    = 5164544;                  // 64
static constexpr size_t OFF_RVEC  = 5164608;                  // 8192
// total ~ 20.7 MB

__device__ __forceinline__ float sigmoidf_(float x){ return 1.f/(1.f + __expf(-x)); }
__device__ __forceinline__ float softplusf_(float x){ return (x > 20.f) ? x : log1pf(__expf(x)); }

// ---------------- K0: gather Xt[k][b] = concat(emb[x[b]], h[b]) transposed --
__global__ __launch_bounds__(256) void gather_xt_kernel(
    const int* __restrict__ x, const float* __restrict__ h,
    const float* __restrict__ emb, float* __restrict__ Xt)
{
  const int idx = blockIdx.x*256 + threadIdx.x;    // 49152 = 768*64
  const int k = idx >> 6, b = idx & 63;
  float v = (k < EE) ? emb[(size_t)x[b]*EE + k] : h[(size_t)b*HH + (k - EE)];
  Xt[(size_t)k*64 + b] = v;
}

// ---------------- K1: gate partials; wave = 4 rows x K-half -----------------
// gpart[kc][j][b], kc plane stride 131072
__global__ __launch_bounds__(256) void lstm_gates_kernel(
    const float* __restrict__ Xt, const float* __restrict__ Wih,
    const float* __restrict__ Whh, float* __restrict__ gpart)
{
  const int tid = threadIdx.x;
  const int lane = tid & 63;
  const int gw = __builtin_amdgcn_readfirstlane(blockIdx.x*4 + (tid >> 6)); // 1024 waves
  const int jg = gw >> 1, kc = gw & 1;
  const int j0 = jg << 2;
  float a0=0.f, a1=0.f, a2=0.f, a3=0.f;
  if (kc == 0){
    const float* w0 = Wih + (size_t)(j0+0)*EE;
    const float* w1 = Wih + (size_t)(j0+1)*EE;
    const float* w2 = Wih + (size_t)(j0+2)*EE;
    const float* w3 = Wih + (size_t)(j0+3)*EE;
    #pragma unroll 4
    for (int k = 0; k < EE; ++k){
      const float xv = Xt[(size_t)k*64 + lane];
      a0 = fmaf(w0[k],xv,a0); a1 = fmaf(w1[k],xv,a1);
      a2 = fmaf(w2[k],xv,a2); a3 = fmaf(w3[k],xv,a3);
    }
    const float* v0 = Whh + (size_t)(j0+0)*HH;
    const float* v1 = Whh + (size_t)(j0+1)*HH;
    const float* v2 = Whh + (size_t)(j0+2)*HH;
    const float* v3 = Whh + (size_t)(j0+3)*HH;
    #pragma unroll 4
    for (int k = 0; k < 128; ++k){
      const float xv = Xt[(size_t)(EE+k)*64 + lane];
      a0 = fmaf(v0[k],xv,a0); a1 = fmaf(v1[k],xv,a1);
      a2 = fmaf(v2[k],xv,a2); a3 = fmaf(v3[k],xv,a3);
    }
  } else {
    const float* v0 = Whh + (size_t)(j0+0)*HH;
    const float* v1 = Whh + (size_t)(j0+1)*HH;
    const float* v2 = Whh + (size_t)(j0+2)*HH;
    const float* v3 = Whh + (size_t)(j0+3)*HH;
    #pragma unroll 4
    for (int k = 128; k < 512; ++k){
      const float xv = Xt[(size_t)(EE+k)*64 + lane];
      a0 = fmaf(v0[k],xv,a0); a1 = fmaf(v1[k],xv,a1);
      a2 = fmaf(v2[k],xv,a2); a3 = fmaf(v3[k],xv,a3);
    }
  }
  float* gp = gpart + (size_t)kc*131072 + (size_t)j0*64 + lane;
  gp[0] = a0; gp[64] = a1; gp[128] = a2; gp[192] = a3;
}

// ---------------- K2: reduce partials + LSTM activations -> h2t ------------
__global__ __launch_bounds__(256) void lstm_act_kernel(
    const float* __restrict__ gpart, const float* __restrict__ bih,
    const float* __restrict__ bhh, const float* __restrict__ c,
    float* __restrict__ h2t)
{
  const int idx = blockIdx.x*256 + threadIdx.x;   // 32768
  const int bb = idx & 63, hh = idx >> 6;
  #define GSUM(j) (gpart[(size_t)(j)*64+bb] + gpart[(size_t)131072+(size_t)(j)*64+bb] + bih[j] + bhh[j])
  const float gi = GSUM(hh);
  const float gf = GSUM(512+hh);
  const float gg = GSUM(1024+hh);
  const float go = GSUM(1536+hh);
  #undef GSUM
  const float c0 = c[(size_t)bb*HH + hh];
  const float c2 = sigmoidf_(gf)*c0 + sigmoidf_(gi)*tanhf(gg);
  h2t[(size_t)hh*64 + bb] = sigmoidf_(go)*tanhf(c2);
}

// ---------------- K3: head partials; wave = 4 rows x K-half -----------------
// hpart[kc][j][b], kc plane stride 33536
__global__ __launch_bounds__(256) void head_gemm_kernel(
    const float* __restrict__ h2t, const float* __restrict__ Ww,
    const float* __restrict__ Wr, float* __restrict__ hpart)
{
  const int tid = threadIdx.x;
  const int lane = tid & 63;
  const int gw = __builtin_amdgcn_readfirstlane(blockIdx.x*4 + (tid >> 6)); // 264 waves
  const int jg = gw >> 1, kc = gw & 1;
  if (jg >= 131) return;
  const int j0 = jg << 2;
  const float* w0 = (j0+0 < 390) ? (Ww + (size_t)(j0+0)*HH) : (Wr + (size_t)(j0+0-390)*HH);
  const float* w1 = (j0+1 < 390) ? (Ww + (size_t)(j0+1)*HH) : (Wr + (size_t)(j0+1-390)*HH);
  const float* w2 = (j0+2 < 390) ? (Ww + (size_t)(j0+2)*HH) : (Wr + (size_t)(j0+2-390)*HH);
  const float* w3 = (j0+3 < 390) ? (Ww + (size_t)(j0+3)*HH) : (Wr + (size_t)(j0+3-390)*HH);
  const int k0 = kc << 8;
  float a0=0.f, a1=0.f, a2=0.f, a3=0.f;
  #pragma unroll 4
  for (int k = k0; k < k0+256; ++k){
    const float xv = h2t[(size_t)k*64 + lane];
    a0 = fmaf(w0[k],xv,a0); a1 = fmaf(w1[k],xv,a1);
    a2 = fmaf(w2[k],xv,a2); a3 = fmaf(w3[k],xv,a3);
  }
  float* hp = hpart + (size_t)kc*33536 + (size_t)j0*64 + lane;
  hp[0] = a0; hp[64] = a1; hp[128] = a2; hp[192] = a3;
}

// ---------------- K4: interpret heads -> params[b] -------------------------
// params stride 544: [0:128] kwE, [128:256] krE, [256:384] a, [384:512] e,
// 512+: {beta_w,g_w,sw0,sw1,sw2,r_w, beta_r,g_r,sr0,sr1,sr2,r_r, nkw,nkr,C_akr,Ca2}
__global__ void interpret_kernel(const float* __restrict__ hp,
                                 const float* __restrict__ bw,
                                 const float* __restrict__ br,
                                 float* __restrict__ params)
{
  const int b = blockIdx.x, l = threadIdx.x;   // 64 threads
  float* P = params + (size_t)b*544;
  #define OC(j) (hp[(size_t)(j)*64+b] + hp[(size_t)33536+(size_t)(j)*64+b])
  float skw = 0.f, skr = 0.f, sakr = 0.f, sa2 = 0.f;
  #pragma unroll
  for (int f = l; f < 128; f += 64){
    float kwE = OC(f) + bw[f] + EPSF;
    float ee  = sigmoidf_(OC(134+f) + bw[134+f]);
    float aa  = OC(262+f) + bw[262+f];
    float krE = OC(390+f) + br[f] + EPSF;
    P[f] = kwE; P[128+f] = krE; P[256+f] = aa; P[384+f] = ee;
    skw = fmaf(kwE,kwE,skw); skr = fmaf(krE,krE,skr);
    sakr = fmaf(aa,krE,sakr); sa2 = fmaf(aa,aa,sa2);
  }
  #pragma unroll
  for (int m = 32; m >= 1; m >>= 1){
    skw += __shfl_xor(skw,m); skr += __shfl_xor(skr,m);
    sakr += __shfl_xor(sakr,m); sa2 += __shfl_xor(sa2,m);
  }
  if (l == 0){
    P[512+0] = softplusf_(OC(128) + bw[128]);
    P[512+1] = sigmoidf_(OC(129) + bw[129]);
    {
      float x0 = OC(130)+bw[130], x1 = OC(131)+bw[131], x2 = OC(132)+bw[132];
      float mm = fmaxf(x0, fmaxf(x1, x2));
      float e0 = __expf(x0-mm), e1 = __expf(x1-mm), e2 = __expf(x2-mm);
      float s = e0+e1+e2;
      P[512+2] = e0/s; P[512+3] = e1/s; P[512+4] = e2/s;
    }
    P[512+5] = 1.f + softplusf_(OC(133) + bw[133]);
    P[512+6] = softplusf_(OC(518) + br[128]);
    P[512+7] = sigmoidf_(OC(519) + br[129]);
    {
      float x0 = OC(520)+br[130], x1 = OC(521)+br[131], x2 = OC(522)+br[132];
      float mm = fmaxf(x0, fmaxf(x1, x2));
      float e0 = __expf(x0-mm), e1 = __expf(x1-mm), e2 = __expf(x2-mm);
      float s = e0+e1+e2;
      P[512+8] = e0/s; P[512+9] = e1/s; P[512+10] = e2/s;
    }
    P[512+11] = 1.f + softplusf_(OC(523) + br[133]);
    P[512+12] = sqrtf(skw); P[512+13] = sqrtf(skr);
    P[512+14] = sakr;       P[512+15] = sa2;
  }
  #undef OC
}

// ---------------- K5: big pass A — per-row scalars over bank ---------------
// per row: zw = beta_w*cos-sim ; q4 = {S2, S3, C_akr-S4, S5-S6} ; q1 = Ca2-2S7+S8
__global__ __launch_bounds__(256) void pass_a_kernel(
    const float* __restrict__ bank, const float* __restrict__ params,
    float* __restrict__ zw, float4* __restrict__ q4, float* __restrict__ q1)
{
  const int blk = blockIdx.x;            // 2048 = 64 b * 32 chunks
  const int b = blk >> 5, chunk = blk & 31;
  const int tid = threadIdx.x;
  const int wv = tid >> 6, lane = tid & 63;
  const int fslot = lane & 7, rsub = lane >> 3;   // 8 lanes per row, 16 f each
  const float* P = params + (size_t)b*544;
  const int fb = fslot << 4;
  float kw[16], kr[16], av[16], ev[16];
  #pragma unroll
  for (int i = 0; i < 16; ++i){
    kw[i] = P[fb+i]; kr[i] = P[128+fb+i]; av[i] = P[256+fb+i]; ev[i] = P[384+fb+i];
  }
  const float beta_w = P[512+0], nkw = P[512+12];
  const float C_akr = P[512+14], Ca2 = P[512+15];
  for (int it = 0; it < 8; ++it){
    const int n = (chunk << 8) + (it << 5) + (wv << 3) + rsub;
    const size_t row = (size_t)b*NN + n;
    const float4* m4 = reinterpret_cast<const float4*>(bank + row*FF + fb);
    float mv[16];
    *reinterpret_cast<float4*>(&mv[0])  = m4[0];
    *reinterpret_cast<float4*>(&mv[4])  = m4[1];
    *reinterpret_cast<float4*>(&mv[8])  = m4[2];
    *reinterpret_cast<float4*>(&mv[12]) = m4[3];
    float s1=0.f,s2=0.f,s3=0.f,s4=0.f,s5=0.f,s6=0.f,s7=0.f,s8=0.f;
    #pragma unroll
    for (int i = 0; i < 16; ++i){
      const float m = mv[i], u = m + EPSF, em = ev[i]*m;
      s1 = fmaf(u,kw[i],s1);  s2 = fmaf(u,u,s2);
      s3 = fmaf(u,kr[i],s3);  s4 = fmaf(em,kr[i],s4);
      s5 = fmaf(u,av[i],s5);  s6 = fmaf(u,em,s6);
      s7 = fmaf(av[i],em,s7); s8 = fmaf(em,em,s8);
    }
    #pragma unroll
    for (int mm = 1; mm < 8; mm <<= 1){
      s1 += __shfl_xor(s1,mm); s2 += __shfl_xor(s2,mm);
      s3 += __shfl_xor(s3,mm); s4 += __shfl_xor(s4,mm);
      s5 += __shfl_xor(s5,mm); s6 += __shfl_xor(s6,mm);
      s7 += __shfl_xor(s7,mm); s8 += __shfl_xor(s8,mm);
    }
    if (fslot == 0){
      float sim = s1 / fmaxf(sqrtf(s2)*nkw, 1e-8f);
      zw[row] = beta_w * sim;
      q4[row] = make_float4(s2, s3, C_akr - s4, s5 - s6);
      q1[row] = Ca2 - 2.f*s7 + s8;
    }
  }
}

// ---------------- block reductions for K6 ----------------------------------
__device__ __forceinline__ float blockMax1024(float v, float* red, int tid){
  #pragma unroll
  for (int m = 32; m >= 1; m >>= 1) v = fmaxf(v, __shfl_xor(v,m));
  __syncthreads();
  if ((tid & 63) == 0) red[tid >> 6] = v;
  __syncthreads();
  if (tid == 0){
    float r = red[0];
    #pragma unroll
    for (int i = 1; i < 16; ++i) r = fmaxf(r, red[i]);
    red[16] = r;
  }
  __syncthreads();
  return red[16];
}
__device__ __forceinline__ float blockSum1024(float v, float* red, int tid){
  #pragma unroll
  for (int m = 32; m >= 1; m >>= 1) v += __shfl_xor(v,m);
  __syncthreads();
  if ((tid & 63) == 0) red[tid >> 6] = v;
  __syncthreads();
  if (tid == 0){
    float r = 0.f;
    #pragma unroll
    for (int i = 0; i < 16; ++i) r += red[i];
    red[16] = r;
  }
  __syncthreads();
  return red[16];
}

// ---------------- K6: per-batch softmax/conv/sharpen pipeline x2 -----------
__global__ __launch_bounds__(1024) void head_pipeline_kernel(
    const float* __restrict__ zw, const float4* __restrict__ q4,
    const float* __restrict__ q1,
    const float* __restrict__ w_write, const float* __restrict__ w_read,
    const float* __restrict__ params,
    float* __restrict__ wrg, float* __restrict__ wrwwg, float* __restrict__ T3g)
{
  __shared__ float wa[NN];
  __shared__ float red[32];
  const int b = blockIdx.x;
  const int tid = threadIdx.x;
  const float* P = params + (size_t)b*544 + 512;
  const float g_w = P[1], sw0 = P[2], sw1 = P[3], sw2 = P[4], r_w = P[5];
  const float beta_r = P[6], g_r = P[7], sr0 = P[8], sr1 = P[9], sr2 = P[10], r_r = P[11];
  const float nkr = P[13];
  const size_t base = (size_t)b*NN;
  float cv[8], wwreg[8];

  // ======== write head ========
  float lm = -1e30f;
  #pragma unroll
  for (int i = 0; i < 8; ++i){ int n = tid + (i<<10); float z = zw[base+n]; wa[n] = z; lm = fmaxf(lm,z); }
  float M = blockMax1024(lm, red, tid);
  float ls = 0.f;
  #pragma unroll
  for (int i = 0; i < 8; ++i){ int n = tid + (i<<10); float e = __expf(wa[n]-M); wa[n] = e; ls += e; }
  float S = blockSum1024(ls, red, tid);
  const float invS = 1.f/S;
  #pragma unroll
  for (int i = 0; i < 8; ++i){ int n = tid + (i<<10); wa[n] = wa[n]*invS + (1.f-g_w)*w_write[base+n]; }
  __syncthreads();
  #pragma unroll
  for (int i = 0; i < 8; ++i){ int n = tid + (i<<10);
    cv[i] = sw0*wa[(n+NN-1)&(NN-1)] + sw1*wa[n] + sw2*wa[(n+1)&(NN-1)]; }
  __syncthreads();
  float lp = 0.f;
  #pragma unroll
  for (int i = 0; i < 8; ++i){ int n = tid + (i<<10); float p = __expf(r_w*__logf(cv[i])); wa[n] = p; lp += p; }
  float Sp = blockSum1024(lp, red, tid);
  float inv = 1.f/(Sp + EPSF);
  #pragma unroll
  for (int i = 0; i < 8; ++i){ wwreg[i] = wa[tid + (i<<10)]*inv; }
  __syncthreads();

  // ======== read head (bank2 stats reconstructed from q4/q1 + ww) ========
  lm = -1e30f;
  #pragma unroll
  for (int i = 0; i < 8; ++i){
    int n = tid + (i<<10);
    const size_t row = base + n;
    const float4 q = q4[row];     // {S2, S3, C_akr-S4, S5-S6}
    const float qq = q1[row];     // Ca2 - 2S7 + S8
    float ww = wwreg[i];
    float num = q.y + ww*q.z;
    float d2  = q.x + 2.f*ww*q.w + ww*ww*qq;
    float den = sqrtf(d2)*nkr;
    float z = beta_r * (num / fmaxf(den, 1e-8f));
    wa[n] = z; lm = fmaxf(lm,z);
  }
  M = blockMax1024(lm, red, tid);
  ls = 0.f;
  #pragma unroll
  for (int i = 0; i < 8; ++i){ int n = tid + (i<<10); float e = __expf(wa[n]-M); wa[n] = e; ls += e; }
  S = blockSum1024(ls, red, tid);
  const float invS2 = 1.f/S;
  #pragma unroll
  for (int i = 0; i < 8; ++i){ int n = tid + (i<<10); wa[n] = wa[n]*invS2 + (1.f-g_r)*w_read[base+n]; }
  __syncthreads();
  #pragma unroll
  for (int i = 0; i < 8; ++i){ int n = tid + (i<<10);
    cv[i] = sr0*wa[(n+NN-1)&(NN-1)] + sr1*wa[n] + sr2*wa[(n+1)&(NN-1)]; }
  __syncthreads();
  lp = 0.f;
  #pragma unroll
  for (int i = 0; i < 8; ++i){ int n = tid + (i<<10); float p = __expf(r_r*__logf(cv[i])); wa[n] = p; lp += p; }
  Sp = blockSum1024(lp, red, tid);
  inv = 1.f/(Sp + EPSF);
  float t3 = 0.f;
  #pragma unroll
  for (int i = 0; i < 8; ++i){
    int n = tid + (i<<10);
    float wr_ = wa[n]*inv;
    wrg[base+n] = wr_;
    float xx = wr_*wwreg[i];
    wrwwg[base+n] = xx;
    t3 += xx;
  }
  float T3 = blockSum1024(t3, red, tid);
  if (tid == 0) T3g[b] = T3;
}

// ---------------- K7: big pass D — weighted reductions over bank -----------
// REVERSED traversal: consume the L3-resident tail of bank (written by pass_a) first.
__global__ __launch_bounds__(256) void pass_d_kernel(
    const float* __restrict__ bank, const float* __restrict__ wrg,
    const float* __restrict__ wrwwg, float* __restrict__ pT)
{
  const int blk = 2047 - blockIdx.x;    // 2048 = 64 b * 32 chunks, reversed
  const int b = blk >> 5, chunk = blk & 31;
  const int tid = threadIdx.x;
  const int st = tid >> 5, li = tid & 31;   // 8 row-streams, 32 f4 each
  float4 a1 = make_float4(0.f,0.f,0.f,0.f);
  float4 a2 = make_float4(0.f,0.f,0.f,0.f);
  for (int it = 31; it >= 0; --it){
    const int n = (chunk << 8) + (it << 3) + st;
    const size_t row = (size_t)b*NN + n;
    const float w1 = wrg[row], w2 = wrwwg[row];
    const float4 m = reinterpret_cast<const float4*>(bank + row*FF)[li];
    a1.x = fmaf(w1,m.x,a1.x); a1.y = fmaf(w1,m.y,a1.y);
    a1.z = fmaf(w1,m.z,a1.z); a1.w = fmaf(w1,m.w,a1.w);
    a2.x = fmaf(w2,m.x,a2.x); a2.y = fmaf(w2,m.y,a2.y);
    a2.z = fmaf(w2,m.z,a2.z); a2.w = fmaf(w2,m.w,a2.w);
  }
  __shared__ float lds[8*256];
  *reinterpret_cast<float4*>(&lds[st*256 + li*4]) = a1;
  *reinterpret_cast<float4*>(&lds[st*256 + 128 + li*4]) = a2;
  __syncthreads();
  float s = 0.f;
  #pragma unroll
  for (int k = 0; k < 8; ++k) s += lds[k*256 + tid];
  pT[(size_t)blk*256 + tid] = s;
}

// ---------------- K7b: reduce partials -> rvec ------------------------------
__global__ __launch_bounds__(256) void rvec_kernel(
    const float* __restrict__ pT, const float* __restrict__ params,
    const float* __restrict__ T3g, float* __restrict__ rvec)
{
  const int gid = blockIdx.x*256 + threadIdx.x;   // 8192
  const int b = gid >> 7, f = gid & 127;
  float t1 = 0.f, t2 = 0.f;
  for (int cc = 0; cc < 32; ++cc){
    const float* p = pT + (size_t)((b<<5) + cc)*256;
    t1 += p[f]; t2 += p[128+f];
  }
  const float* P = params + (size_t)b*544;
  rvec[gid] = t1 - P[384+f]*t2 + P[256+f]*T3g[b];
}

// ---------------- K8: out = rvec @ W_out^T + b_out --------------------------
__global__ __launch_bounds__(256) void out_gemm_kernel(
    const float* __restrict__ rvec, const float* __restrict__ Wout,
    const float* __restrict__ bout, float* __restrict__ out)
{
  const int tid = threadIdx.x;
  const int wv = __builtin_amdgcn_readfirstlane(tid >> 6);
  const int lane = tid & 63;     // lane = batch
  const int j0 = blockIdx.x*32 + wv*8;
  float acc[8];
  #pragma unroll
  for (int jj = 0; jj < 8; ++jj){ int j = j0 + jj; acc[jj] = (j < VV) ? bout[j] : 0.f; }
  for (int fc = 0; fc < 128; fc += 32){
    float rv[32];
    #pragma unroll
    for (int i = 0; i < 32; ++i) rv[i] = rvec[lane*128 + fc + i];
    #pragma unroll
    for (int jj = 0; jj < 8; ++jj){
      const int j = j0 + jj;
      if (j < VV){
        const float* w = Wout + (size_t)j*128 + fc;
        #pragma unroll
        for (int i = 0; i < 32; ++i) acc[jj] = fmaf(w[i], rv[i], acc[jj]);
      }
    }
  }
  #pragma unroll
  for (int jj = 0; jj < 8; ++jj){
    int j = j0 + jj;
    if (j < VV) out[(size_t)lane*VV + j] = acc[jj];
  }
}

// ---------------------------------------------------------------------------
extern "C" void kernel_launch(void* const* d_in, const int* in_sizes, int n_in,
                              void* d_out, int out_size, void* d_ws, size_t ws_size,
                              hipStream_t stream)
{
  const int*   x       = (const int*)  d_in[0];
  const float* h       = (const float*)d_in[1];
  const float* c       = (const float*)d_in[2];
  const float* w_read  = (const float*)d_in[3];
  const float* w_write = (const float*)d_in[4];
  const float* bank    = (const float*)d_in[5];
  const float* emb     = (const float*)d_in[6];
  const float* Wih     = (const float*)d_in[7];
  const float* bih     = (const float*)d_in[8];
  const float* Whh     = (const float*)d_in[9];
  const float* bhh     = (const float*)d_in[10];
  const float* Wr      = (const float*)d_in[11];
  const float* br      = (const float*)d_in[12];
  const float* Ww      = (const float*)d_in[13];
  const float* bw      = (const float*)d_in[14];
  const float* Wout    = (const float*)d_in[15];
  const float* bout    = (const float*)d_in[16];
  float* out = (float*)d_out;
  float* ws  = (float*)d_ws;

  float* Xt    = ws + OFF_XT;
  float* gpart = ws + OFF_GPART;
  float* h2t   = ws + OFF_H2T;
  float* hpart = ws + OFF_HPART;
  float* par   = ws + OFF_PAR;
  float* zwp   = ws + OFF_ZW;
  float4* q4p  = reinterpret_cast<float4*>(ws + OFF_Q4);
  float* q1p   = ws + OFF_Q1;
  float* wrp   = ws + OFF_WR;
  float* wrwwp = ws + OFF_WRWW;
  float* pTp   = ws + OFF_PT;
  float* T3p   = ws + OFF_T3;
  float* rvp   = ws + OFF_RVEC;

  hipLaunchKernelGGL(gather_xt_kernel,     dim3(192),  dim3(256), 0, stream, x, h, emb, Xt);
  hipLaunchKernelGGL(lstm_gates_kernel,    dim3(256),  dim3(256), 0, stream, Xt, Wih, Whh, gpart);
  hipLaunchKernelGGL(lstm_act_kernel,      dim3(128),  dim3(256), 0, stream, gpart, bih, bhh, c, h2t);
  hipLaunchKernelGGL(head_gemm_kernel,     dim3(66),   dim3(256), 0, stream, h2t, Ww, Wr, hpart);
  hipLaunchKernelGGL(interpret_kernel,     dim3(64),   dim3(64),  0, stream, hpart, bw, br, par);
  hipLaunchKernelGGL(pass_a_kernel,        dim3(2048), dim3(256), 0, stream, bank, par, zwp, q4p, q1p);
  hipLaunchKernelGGL(head_pipeline_kernel, dim3(64),   dim3(1024),0, stream, zwp, q4p, q1p, w_write, w_read, par, wrp, wrwwp, T3p);
  hipLaunchKernelGGL(pass_d_kernel,        dim3(2048), dim3(256), 0, stream, bank, wrp, wrwwp, pTp);
  hipLaunchKernelGGL(rvec_kernel,          dim3(32),   dim3(256), 0, stream, pTp, par, T3p, rvp);
  hipLaunchKernelGGL(out_gemm_kernel,      dim3(313),  dim3(256), 0, stream, rvp, Wout, bout, out);
}